// Round 22
// baseline (165.129 us; speedup 1.0000x reference)
//
#include <hip/hip_runtime.h>

// HellingerDistance: out[n][m] = 0.5*(rowsum_a[n] + rowsum_b[m]) - sqrt(a[n])·sqrt(b[m])
// N = M = 8192, D = 1024, f32 in/out.
// Round 22: r20 i8/BK=128 structure made PERSISTENT: 256 blocks (1/CU), each
// owns 4 adjacent 256^2 tiles (same brow -> A-panel L2/L3 reuse). The staging
// ring continues seamlessly across tiles (it==3 stages next tile's K0/K1), so
// no per-block cold prologue / end-of-block store drain for 3 of 4 tiles.
// Gate counts re-derived with epilogue stores in the vmcnt FIFO (see trace).

#define NM 8192
#define DD 1024

typedef __attribute__((ext_vector_type(4))) int i32x4;
typedef __attribute__((ext_vector_type(16))) int i32x16;
typedef __attribute__((ext_vector_type(8))) short bf16x8;
typedef __attribute__((ext_vector_type(4))) float f32x4;

#define AS1 __attribute__((address_space(1)))
#define AS3 __attribute__((address_space(3)))

#define THROTTLE_LGKM0 asm volatile("s_waitcnt lgkmcnt(0)")
#define GATE_VM(n) asm volatile("s_waitcnt vmcnt(" #n ")" ::: "memory")
#define BAR __builtin_amdgcn_s_barrier()

// f32 -> bf16 round-to-nearest-even (fallback kernel only)
static __device__ __forceinline__ unsigned short f2bf(float f) {
  unsigned int u = __float_as_uint(f);
  u += 0x7FFFu + ((u >> 16) & 1u);
  return (unsigned short)(u >> 16);
}

// ---------------- kernel 1: sqrt -> i8 (x127), exact f32 rowsums -----------
__global__ __launch_bounds__(256)
void hell_prep8(const float* __restrict__ A, const float* __restrict__ B,
                signed char* __restrict__ QA, signed char* __restrict__ QB,
                float* __restrict__ RA, float* __restrict__ RB) {
  __shared__ float wsum[4];
  const int row = blockIdx.x & (NM - 1);
  const bool isB = blockIdx.x >= NM;
  const float* src = (isB ? B : A) + (size_t)row * DD;
  signed char* dst = (isB ? QB : QA) + (size_t)row * DD;
  const int t = threadIdx.x;
  const float4 v = ((const float4*)src)[t];
  char4 q;
  q.x = (signed char)__float2int_rn(sqrtf(v.x) * 127.0f);
  q.y = (signed char)__float2int_rn(sqrtf(v.y) * 127.0f);
  q.z = (signed char)__float2int_rn(sqrtf(v.z) * 127.0f);
  q.w = (signed char)__float2int_rn(sqrtf(v.w) * 127.0f);
  ((char4*)dst)[t] = q;
  float s = (v.x + v.y) + (v.z + v.w);
#pragma unroll
  for (int m = 1; m < 64; m <<= 1) s += __shfl_xor(s, m, 64);
  if ((t & 63) == 0) wsum[t >> 6] = s;
  __syncthreads();
  if (t == 0) (isB ? RB : RA)[row] = wsum[0] + wsum[1] + wsum[2] + wsum[3];
}

// ---------------- kernel 2: persistent 256^2 i8 GEMM, BK=128 ---------------
// LDS buf d at d*65536: A [256 rows][128 k] i8 (128B/row = 8 chunks) at +0,
// B at +32768. Chunk c of row r stored at c ^ (r&7) (both-sides swizzle).
// Gate-FIFO trace (per wave, in-order completion):
//  prologue [E0(8),O1(8)]; it-loop invariant: gate8 -> oldest tile landed
//  with the 8 newest (next stage) in flight. Tile boundary: [E0',O1',St128];
//  gate8 forces E0'+O1'+120 stores (L2-ack, cheap) -> correct and non-draining.
__global__ __launch_bounds__(512, 1)
void hell_gemm21(const signed char* __restrict__ QA,
                 const signed char* __restrict__ QB,
                 const float* __restrict__ RA, const float* __restrict__ RB,
                 float* __restrict__ C) {
  __shared__ __attribute__((aligned(16))) char lds[131072];

  const int t = threadIdx.x;
  const int lane = t & 63;
  const int wave = t >> 6;
  const int wm = wave >> 2;   // 0..1 -> rows wm*128
  const int wn = wave & 3;    // 0..3 -> cols wn*64

  // 256 blocks; block b owns tiles s = 128*(b&7) + (b>>3)*4 + j, j=0..3
  // (b&7 selects XCD-chunk; 4 consecutive s share brow -> A-panel reuse)
  const int b = blockIdx.x;
  const int sbase = (b & 7) * 128 + (b >> 3) * 4;

  // staging: thread t covers row (t>>3)+i*64, chunk t&7; source pre-swizzled
  const int sw = (t & 7) ^ ((t >> 3) & 7);

  const int kg = lane >> 5;   // k-group (0..1)
  const int lo5 = lane & 31;  // row/col within 32
  const int x7 = lo5 & 7;

  // read slot byte offsets for the 4 k-steps: ((ks*2+kg)^x7)<<4
  int slot[4];
#pragma unroll
  for (int ks = 0; ks < 4; ++ks) slot[ks] = (((ks * 2 + kg) ^ x7) << 4);

  const char* aE = lds + (wm * 128 + lo5) * 128;
  const char* bE = lds + 32768 + (wn * 64 + lo5) * 128;
  const char* aO = aE + 65536;
  const char* bO = bE + 65536;

  i32x4 af[4];       // A fragments, one k-step
  i32x4 bf2[2][4];   // B fragments, whole K-tile [n][ks]

#define GL(P, LOFF)                                                             \
  __builtin_amdgcn_global_load_lds((const AS1 unsigned int*)(P),                \
      (AS3 unsigned int*)(lds + (LOFF) + t * 16), 16, 0, 0)
// stage one 256x128 i8 matrix tile = 4 gloads/thread (32 KB)
#define STAGE(MAT, BASE, KT, LOFF)                                              \
  do {                                                                          \
    const signed char* g_ =                                                     \
        (MAT) + (size_t)((BASE) + (t >> 3)) * DD + (size_t)(KT) * 128 + sw * 16; \
    _Pragma("unroll")                                                           \
    for (int i_ = 0; i_ < 4; ++i_)                                              \
      GL(g_ + (size_t)(i_ * 64) * DD, (LOFF) + i_ * 8192);                      \
  } while (0)

#define LDB_ALL(BB)                                                             \
  do {                                                                          \
    _Pragma("unroll")                                                           \
    for (int n_ = 0; n_ < 2; ++n_)                                              \
      _Pragma("unroll")                                                         \
      for (int ks_ = 0; ks_ < 4; ++ks_)                                         \
        bf2[n_][ks_] = *(const i32x4*)((BB) + n_ * 4096 + slot[ks_]);           \
  } while (0)

#define LDA4(AB, ks)                                                            \
  do {                                                                          \
    _Pragma("unroll")                                                           \
    for (int m_ = 0; m_ < 4; ++m_)                                              \
      af[m_] = *(const i32x4*)((AB) + m_ * 4096 + slot[ks]);                    \
  } while (0)

#define MFMA8(ks)                                                               \
  do {                                                                          \
    __builtin_amdgcn_s_setprio(1);                                              \
    _Pragma("unroll")                                                           \
    for (int m_ = 0; m_ < 4; ++m_)                                              \
      _Pragma("unroll")                                                         \
      for (int n_ = 0; n_ < 2; ++n_)                                            \
        acc[m_][n_] = __builtin_amdgcn_mfma_i32_32x32x32_i8(                    \
            af[m_], bf2[n_][ks], acc[m_][n_], 0, 0, 0);                         \
    __builtin_amdgcn_s_setprio(0);                                              \
  } while (0)

  // prologue for tile j=0: E<-K0, O<-K1
  {
    const int s0 = sbase;
    const int br0 = (s0 >> 5) * 256, bc0 = (s0 & 31) * 256;
    STAGE(QA, br0, 0, 0);
    STAGE(QB, bc0, 0, 32768);
    STAGE(QA, br0, 1, 65536);
    STAGE(QB, bc0, 1, 65536 + 32768);
  }

#pragma unroll 1
  for (int j = 0; j < 4; ++j) {
    const int s1 = sbase + j;
    const int brow = (s1 >> 5) * 256, bcol = (s1 & 31) * 256;
    const int brow2 = ((s1 + 1) >> 5) * 256, bcol2 = ((s1 + 1) & 31) * 256;

    i32x16 acc[4][2];
#pragma unroll
    for (int m = 0; m < 4; ++m)
#pragma unroll
      for (int n = 0; n < 2; ++n)
#pragma unroll
        for (int r = 0; r < 16; ++r) acc[m][n][r] = 0;

#pragma unroll 1
    for (int it = 0; it < 4; ++it) {
      const bool lit = (it == 3);
      const bool fin = (j == 3) && lit;
      const int brN = lit ? brow2 : brow;  // staging targets: cross to next
      const int bcN = lit ? bcol2 : bcol;  // tile at the tile's last iteration
      const int kE = lit ? 0 : 2 * it + 2;
      const int kO = lit ? 1 : 2 * it + 3;

      // gate: E's 8 (oldest) landed; BAR -> whole block sees the tile
      GATE_VM(8);
      BAR;
      // E compute: 4 k-step phases
      LDB_ALL(bE); LDA4(aE, 0);
      THROTTLE_LGKM0; MFMA8(0);
      LDA4(aE, 1); THROTTLE_LGKM0; MFMA8(1);
      LDA4(aE, 2); THROTTLE_LGKM0; MFMA8(2);
      LDA4(aE, 3); THROTTLE_LGKM0; MFMA8(3);
      BAR;  // all waves' E reads complete -> E buffer free
      if (!fin) {
        STAGE(QA, brN, kE, 0);
        STAGE(QB, bcN, kE, 32768);
        GATE_VM(8);   // O landed (new E's 8 stay in flight)
      } else {
        GATE_VM(0);   // final drain: O landed
      }
      BAR;
      // O compute
      LDB_ALL(bO); LDA4(aO, 0);
      THROTTLE_LGKM0; MFMA8(0);
      LDA4(aO, 1); THROTTLE_LGKM0; MFMA8(1);
      LDA4(aO, 2); THROTTLE_LGKM0; MFMA8(2);
      LDA4(aO, 3); THROTTLE_LGKM0; MFMA8(3);
      BAR;  // all O reads complete -> O buffer free
      if (!fin) {
        STAGE(QA, brN, kO, 65536);
        STAGE(QB, bcN, kO, 65536 + 32768);
      }
    }

    // per-tile epilogue (stores enter vmcnt FIFO; next tile's gate8 handles)
    {
      const float inv = 1.0f / 16129.0f;  // 1/127^2
      float hrb[2];
#pragma unroll
      for (int n = 0; n < 2; ++n)
        hrb[n] = 0.5f * RB[bcol + wn * 64 + n * 32 + lo5];
#pragma unroll
      for (int m = 0; m < 4; ++m) {
#pragma unroll
        for (int r = 0; r < 16; ++r) {
          const int row = (r & 3) + 8 * (r >> 2) + 4 * kg;
          const int R = wm * 128 + m * 32 + row;
          const float ha = 0.5f * RA[brow + R];
          float* orow = C + (size_t)(brow + R) * NM + bcol;
#pragma unroll
          for (int n = 0; n < 2; ++n)
            orow[wn * 64 + n * 32 + lo5] = ha + hrb[n] - (float)acc[m][n][r] * inv;
        }
      }
    }
  }

#undef MFMA8
#undef LDA4
#undef LDB_ALL
#undef STAGE
#undef GL
}

// ---------------- fallback: bf16 fused kernel (if ws too small) ------------
static __device__ __forceinline__ int swz(int row, int colbytes) {
  return (row * 128 + colbytes) ^ ((row & 7) << 4);
}

__global__ __launch_bounds__(256, 2)
void hellinger_fused(const float* __restrict__ A, const float* __restrict__ B,
                     float* __restrict__ C) {
  __shared__ unsigned short As[128 * 64];
  __shared__ unsigned short Bs[128 * 64];
  __shared__ float sA[128];
  __shared__ float sB[128];

  const int t = threadIdx.x;
  const int lane = t & 63;
  const int wave = t >> 6;
  const int wrow = (wave >> 1) * 64;
  const int wcol = (wave & 1) * 64;
  const int brow = blockIdx.y * 128;
  const int bcol = blockIdx.x * 128;
  const int sr = t >> 4;
  const int sc = (t & 15) * 4;

  const float* ap = A + (size_t)(brow + sr) * DD + sc;
  const float* bp = B + (size_t)(bcol + sr) * DD + sc;

  float racc[8], cacc[8];
#pragma unroll
  for (int i = 0; i < 8; ++i) { racc[i] = 0.f; cacc[i] = 0.f; }

  f32x4 acc[4][4];
#pragma unroll
  for (int m = 0; m < 4; ++m)
#pragma unroll
    for (int n = 0; n < 4; ++n) acc[m][n] = (f32x4){0.f, 0.f, 0.f, 0.f};

  for (int kt = 0; kt < DD / 64; ++kt) {
#pragma unroll
    for (int i = 0; i < 8; ++i) {
      const float4 v = *(const float4*)(ap + (size_t)(i * 16) * DD + kt * 64);
      racc[i] += (v.x + v.y) + (v.z + v.w);
      ushort4 p;
      p.x = f2bf(sqrtf(v.x)); p.y = f2bf(sqrtf(v.y));
      p.z = f2bf(sqrtf(v.z)); p.w = f2bf(sqrtf(v.w));
      *(ushort4*)((char*)As + swz(i * 16 + sr, sc * 2)) = p;
    }
#pragma unroll
    for (int i = 0; i < 8; ++i) {
      const float4 v = *(const float4*)(bp + (size_t)(i * 16) * DD + kt * 64);
      cacc[i] += (v.x + v.y) + (v.z + v.w);
      ushort4 p;
      p.x = f2bf(sqrtf(v.x)); p.y = f2bf(sqrtf(v.y));
      p.z = f2bf(sqrtf(v.z)); p.w = f2bf(sqrtf(v.w));
      *(ushort4*)((char*)Bs + swz(i * 16 + sr, sc * 2)) = p;
    }
    __syncthreads();
#pragma unroll
    for (int kk = 0; kk < 2; ++kk) {
      const int koffb = kk * 64 + (lane >> 4) * 16;
      bf16x8 af[4], bfr[4];
#pragma unroll
      for (int m = 0; m < 4; ++m)
        af[m] = *(const bf16x8*)((const char*)As + swz(wrow + m * 16 + (lane & 15), koffb));
#pragma unroll
      for (int n = 0; n < 4; ++n)
        bfr[n] = *(const bf16x8*)((const char*)Bs + swz(wcol + n * 16 + (lane & 15), koffb));
#pragma unroll
      for (int m = 0; m < 4; ++m)
#pragma unroll
        for (int n = 0; n < 4; ++n)
          acc[m][n] = __builtin_amdgcn_mfma_f32_16x16x32_bf16(af[m], bfr[n], acc[m][n], 0, 0, 0);
    }
    __syncthreads();
  }

#pragma unroll
  for (int i = 0; i < 8; ++i) {
#pragma unroll
    for (int mask = 1; mask < 16; mask <<= 1) {
      racc[i] += __shfl_xor(racc[i], mask, 64);
      cacc[i] += __shfl_xor(cacc[i], mask, 64);
    }
  }
  if ((t & 15) == 0) {
#pragma unroll
    for (int i = 0; i < 8; ++i) { sA[i * 16 + sr] = racc[i]; sB[i * 16 + sr] = cacc[i]; }
  }
  __syncthreads();

#pragma unroll
  for (int m = 0; m < 4; ++m) {
    const int rbase = wrow + m * 16 + (lane >> 4) * 4;
#pragma unroll
    for (int j = 0; j < 4; ++j) {
      const int row = rbase + j;
      const float ha = 0.5f * sA[row];
      float* orow = C + (size_t)(brow + row) * NM + bcol;
#pragma unroll
      for (int n = 0; n < 4; ++n) {
        const int col = wcol + n * 16 + (lane & 15);
        orow[col] = ha + 0.5f * sB[col] - acc[m][n][j];
      }
    }
  }
}

extern "C" void kernel_launch(void* const* d_in, const int* in_sizes, int n_in,
                              void* d_out, int out_size, void* d_ws, size_t ws_size,
                              hipStream_t stream) {
  const float* a = (const float*)d_in[0];
  const float* b = (const float*)d_in[1];
  float* out = (float*)d_out;

  const size_t mat_bytes = (size_t)NM * DD;  // 8 MB per i8 matrix
  const size_t need = 2 * mat_bytes + 2 * (size_t)NM * sizeof(float);

  if (ws_size >= need) {
    signed char* QA = (signed char*)d_ws;
    signed char* QB = (signed char*)d_ws + mat_bytes;
    float* RA = (float*)((char*)d_ws + 2 * mat_bytes);
    float* RB = RA + NM;
    hipLaunchKernelGGL(hell_prep8, dim3(2 * NM), dim3(256), 0, stream,
                       a, b, QA, QB, RA, RB);
    hipLaunchKernelGGL(hell_gemm21, dim3(256), dim3(512), 0, stream,
                       QA, QB, RA, RB, out);
  } else {
    dim3 grid(NM / 128, NM / 128);
    hipLaunchKernelGGL(hellinger_fused, grid, dim3(256), 0, stream, a, b, out);
  }
}

// Round 23
// 130.605 us; speedup vs baseline: 1.2643x; 1.2643x over previous
//
#include <hip/hip_runtime.h>

// HellingerDistance: out[n][m] = 0.5*(rowsum_a[n] + rowsum_b[m]) - sqrt(a[n])·sqrt(b[m])
// N = M = 8192, D = 1024, f32 in/out.
// FINAL (revert to round-20 best, 129.9 us): i8 cross-term GEMM.
// q = round(sqrt(x)*127) (absmax 0.5 << 1.39 threshold); exact f32 rowsum bias.
// 256x256 tile, BK=128, 8 waves, mfma_i32_32x32x32_i8, both-sides 8-slot XOR
// swizzle (pre-swizzled global source + XOR'd read slots, 0 bank conflicts),
// double-buffered gate->BAR->read->lgkm0->MFMA ring with counted vmcnt(8),
// bijective XCD swizzle. Cumulative: 815 -> 130 us.

#define NM 8192
#define DD 1024

typedef __attribute__((ext_vector_type(4))) int i32x4;
typedef __attribute__((ext_vector_type(16))) int i32x16;
typedef __attribute__((ext_vector_type(8))) short bf16x8;
typedef __attribute__((ext_vector_type(4))) float f32x4;

#define AS1 __attribute__((address_space(1)))
#define AS3 __attribute__((address_space(3)))

#define THROTTLE_LGKM0 asm volatile("s_waitcnt lgkmcnt(0)")
#define GATE_VM(n) asm volatile("s_waitcnt vmcnt(" #n ")" ::: "memory")
#define BAR __builtin_amdgcn_s_barrier()

// f32 -> bf16 round-to-nearest-even (fallback kernel only)
static __device__ __forceinline__ unsigned short f2bf(float f) {
  unsigned int u = __float_as_uint(f);
  u += 0x7FFFu + ((u >> 16) & 1u);
  return (unsigned short)(u >> 16);
}

// ---------------- kernel 1: sqrt -> i8 (x127), exact f32 rowsums -----------
__global__ __launch_bounds__(256)
void hell_prep8(const float* __restrict__ A, const float* __restrict__ B,
                signed char* __restrict__ QA, signed char* __restrict__ QB,
                float* __restrict__ RA, float* __restrict__ RB) {
  __shared__ float wsum[4];
  const int row = blockIdx.x & (NM - 1);
  const bool isB = blockIdx.x >= NM;
  const float* src = (isB ? B : A) + (size_t)row * DD;
  signed char* dst = (isB ? QB : QA) + (size_t)row * DD;
  const int t = threadIdx.x;
  const float4 v = ((const float4*)src)[t];
  char4 q;
  q.x = (signed char)__float2int_rn(sqrtf(v.x) * 127.0f);
  q.y = (signed char)__float2int_rn(sqrtf(v.y) * 127.0f);
  q.z = (signed char)__float2int_rn(sqrtf(v.z) * 127.0f);
  q.w = (signed char)__float2int_rn(sqrtf(v.w) * 127.0f);
  ((char4*)dst)[t] = q;
  float s = (v.x + v.y) + (v.z + v.w);
#pragma unroll
  for (int m = 1; m < 64; m <<= 1) s += __shfl_xor(s, m, 64);
  if ((t & 63) == 0) wsum[t >> 6] = s;
  __syncthreads();
  if (t == 0) (isB ? RB : RA)[row] = wsum[0] + wsum[1] + wsum[2] + wsum[3];
}

// ---------------- kernel 2: 256^2 i8 GEMM, BK=128 --------------------------
// LDS buf d at d*65536: A [256 rows][128 k] i8 (128B/row = 8 chunks) at +0,
// B at +32768. Chunk c (0..7) of row r stored at c ^ (r&7) (both-sides
// swizzle: pre-swizzled global source + XOR'd read slot).
__global__ __launch_bounds__(512, 1)
void hell_gemm19(const signed char* __restrict__ QA,
                 const signed char* __restrict__ QB,
                 const float* __restrict__ RA, const float* __restrict__ RB,
                 float* __restrict__ C) {
  __shared__ __attribute__((aligned(16))) char lds[131072];

  const int t = threadIdx.x;
  const int lane = t & 63;
  const int wave = t >> 6;
  const int wm = wave >> 2;   // 0..1 -> rows wm*128
  const int wn = wave & 3;    // 0..3 -> cols wn*64

  // bijective XCD swizzle: nwg = 1024, 8 XCDs, chunk = 128
  const int wg = blockIdx.x;
  const int s = (wg & 7) * 128 + (wg >> 3);
  const int brow = (s >> 5) * 256;
  const int bcol = (s & 31) * 256;

  // staging: thread t covers row (t>>3)+i*64, chunk t&7; source pre-swizzled
  const int sw = (t & 7) ^ ((t >> 3) & 7);

  const int kg = lane >> 5;   // k-group (0..1)
  const int lo5 = lane & 31;  // row/col within 32
  const int x7 = lo5 & 7;

  // read slot byte offsets for the 4 k-steps: ((ks*2+kg)^x7)<<4
  int slot[4];
#pragma unroll
  for (int ks = 0; ks < 4; ++ks) slot[ks] = (((ks * 2 + kg) ^ x7) << 4);

  const char* aE = lds + (wm * 128 + lo5) * 128;
  const char* bE = lds + 32768 + (wn * 64 + lo5) * 128;
  const char* aO = aE + 65536;
  const char* bO = bE + 65536;

  i32x16 acc[4][2];
#pragma unroll
  for (int m = 0; m < 4; ++m)
#pragma unroll
    for (int n = 0; n < 2; ++n)
#pragma unroll
      for (int r = 0; r < 16; ++r) acc[m][n][r] = 0;

  i32x4 af[4];       // A fragments, one k-step
  i32x4 bf2[2][4];   // B fragments, whole K-tile [n][ks]

#define GL(P, LOFF)                                                             \
  __builtin_amdgcn_global_load_lds((const AS1 unsigned int*)(P),                \
      (AS3 unsigned int*)(lds + (LOFF) + t * 16), 16, 0, 0)
// stage one 256x128 i8 matrix tile = 4 gloads/thread (32 KB)
#define STAGE(MAT, BASE, KT, LOFF)                                              \
  do {                                                                          \
    const signed char* g_ =                                                     \
        (MAT) + (size_t)((BASE) + (t >> 3)) * DD + (size_t)(KT) * 128 + sw * 16; \
    _Pragma("unroll")                                                           \
    for (int i_ = 0; i_ < 4; ++i_)                                              \
      GL(g_ + (size_t)(i_ * 64) * DD, (LOFF) + i_ * 8192);                      \
  } while (0)

#define LDB_ALL(BB)                                                             \
  do {                                                                          \
    _Pragma("unroll")                                                           \
    for (int n_ = 0; n_ < 2; ++n_)                                              \
      _Pragma("unroll")                                                         \
      for (int ks_ = 0; ks_ < 4; ++ks_)                                         \
        bf2[n_][ks_] = *(const i32x4*)((BB) + n_ * 4096 + slot[ks_]);           \
  } while (0)

#define LDA4(AB, ks)                                                            \
  do {                                                                          \
    _Pragma("unroll")                                                           \
    for (int m_ = 0; m_ < 4; ++m_)                                              \
      af[m_] = *(const i32x4*)((AB) + m_ * 4096 + slot[ks]);                    \
  } while (0)

// 8 independent 32x32x32 i8 MFMAs (distinct acc tiles)
#define MFMA8(ks)                                                               \
  do {                                                                          \
    __builtin_amdgcn_s_setprio(1);                                              \
    _Pragma("unroll")                                                           \
    for (int m_ = 0; m_ < 4; ++m_)                                              \
      _Pragma("unroll")                                                         \
      for (int n_ = 0; n_ < 2; ++n_)                                            \
        acc[m_][n_] = __builtin_amdgcn_mfma_i32_32x32x32_i8(                    \
            af[m_], bf2[n_][ks], acc[m_][n_], 0, 0, 0);                         \
    __builtin_amdgcn_s_setprio(0);                                              \
  } while (0)

  // prologue: stage E(tile0, 8 gloads) then O(tile1, 8 gloads) — FIFO order
  STAGE(QA, brow, 0, 0);
  STAGE(QB, bcol, 0, 32768);
  STAGE(QA, brow, 1, 65536);
  STAGE(QB, bcol, 1, 65536 + 32768);

#pragma unroll 1
  for (int it = 0; it < 4; ++it) {
    const int last = (it == 3);
    // gate: E's 8 (oldest) landed; BAR -> whole block sees the tile
    GATE_VM(8);
    BAR;
    // E compute: 4 k-step phases; reads then lgkm0 then 8 MFMAs
    LDB_ALL(bE); LDA4(aE, 0);
    THROTTLE_LGKM0; MFMA8(0);
    LDA4(aE, 1); THROTTLE_LGKM0; MFMA8(1);
    LDA4(aE, 2); THROTTLE_LGKM0; MFMA8(2);
    LDA4(aE, 3); THROTTLE_LGKM0; MFMA8(3);
    BAR;  // all waves' E reads complete -> E buffer free
    if (!last) {
      STAGE(QA, brow, 2 * it + 2, 0);
      STAGE(QB, bcol, 2 * it + 2, 32768);
      GATE_VM(8);   // O's 8 landed (E-new's 8 stay in flight)
    } else {
      GATE_VM(0);   // drain: O landed
    }
    BAR;
    // O compute
    LDB_ALL(bO); LDA4(aO, 0);
    THROTTLE_LGKM0; MFMA8(0);
    LDA4(aO, 1); THROTTLE_LGKM0; MFMA8(1);
    LDA4(aO, 2); THROTTLE_LGKM0; MFMA8(2);
    LDA4(aO, 3); THROTTLE_LGKM0; MFMA8(3);
    BAR;  // all O reads complete -> O buffer free
    if (!last) {
      STAGE(QA, brow, 2 * it + 3, 65536);
      STAGE(QB, bcol, 2 * it + 3, 65536 + 32768);
    }
  }

#undef MFMA8
#undef LDA4
#undef LDB_ALL
#undef STAGE
#undef GL

  // epilogue: 32x32 C/D layout col=lane&31, row=(r&3)+8*(r>>2)+4*(lane>>5)
  const float inv = 1.0f / 16129.0f;  // 1/127^2
  float hrb[2];
#pragma unroll
  for (int n = 0; n < 2; ++n)
    hrb[n] = 0.5f * RB[bcol + wn * 64 + n * 32 + lo5];
#pragma unroll
  for (int m = 0; m < 4; ++m) {
#pragma unroll
    for (int r = 0; r < 16; ++r) {
      const int row = (r & 3) + 8 * (r >> 2) + 4 * kg;
      const int R = wm * 128 + m * 32 + row;
      const float ha = 0.5f * RA[brow + R];
      float* orow = C + (size_t)(brow + R) * NM + bcol;
#pragma unroll
      for (int n = 0; n < 2; ++n)
        orow[wn * 64 + n * 32 + lo5] = ha + hrb[n] - (float)acc[m][n][r] * inv;
    }
  }
}

// ---------------- fallback: bf16 fused kernel (if ws too small) ------------
static __device__ __forceinline__ int swz(int row, int colbytes) {
  return (row * 128 + colbytes) ^ ((row & 7) << 4);
}

__global__ __launch_bounds__(256, 2)
void hellinger_fused(const float* __restrict__ A, const float* __restrict__ B,
                     float* __restrict__ C) {
  __shared__ unsigned short As[128 * 64];
  __shared__ unsigned short Bs[128 * 64];
  __shared__ float sA[128];
  __shared__ float sB[128];

  const int t = threadIdx.x;
  const int lane = t & 63;
  const int wave = t >> 6;
  const int wrow = (wave >> 1) * 64;
  const int wcol = (wave & 1) * 64;
  const int brow = blockIdx.y * 128;
  const int bcol = blockIdx.x * 128;
  const int sr = t >> 4;
  const int sc = (t & 15) * 4;

  const float* ap = A + (size_t)(brow + sr) * DD + sc;
  const float* bp = B + (size_t)(bcol + sr) * DD + sc;

  float racc[8], cacc[8];
#pragma unroll
  for (int i = 0; i < 8; ++i) { racc[i] = 0.f; cacc[i] = 0.f; }

  f32x4 acc[4][4];
#pragma unroll
  for (int m = 0; m < 4; ++m)
#pragma unroll
    for (int n = 0; n < 4; ++n) acc[m][n] = (f32x4){0.f, 0.f, 0.f, 0.f};

  for (int kt = 0; kt < DD / 64; ++kt) {
#pragma unroll
    for (int i = 0; i < 8; ++i) {
      const float4 v = *(const float4*)(ap + (size_t)(i * 16) * DD + kt * 64);
      racc[i] += (v.x + v.y) + (v.z + v.w);
      ushort4 p;
      p.x = f2bf(sqrtf(v.x)); p.y = f2bf(sqrtf(v.y));
      p.z = f2bf(sqrtf(v.z)); p.w = f2bf(sqrtf(v.w));
      *(ushort4*)((char*)As + swz(i * 16 + sr, sc * 2)) = p;
    }
#pragma unroll
    for (int i = 0; i < 8; ++i) {
      const float4 v = *(const float4*)(bp + (size_t)(i * 16) * DD + kt * 64);
      cacc[i] += (v.x + v.y) + (v.z + v.w);
      ushort4 p;
      p.x = f2bf(sqrtf(v.x)); p.y = f2bf(sqrtf(v.y));
      p.z = f2bf(sqrtf(v.z)); p.w = f2bf(sqrtf(v.w));
      *(ushort4*)((char*)Bs + swz(i * 16 + sr, sc * 2)) = p;
    }
    __syncthreads();
#pragma unroll
    for (int kk = 0; kk < 2; ++kk) {
      const int koffb = kk * 64 + (lane >> 4) * 16;
      bf16x8 af[4], bfr[4];
#pragma unroll
      for (int m = 0; m < 4; ++m)
        af[m] = *(const bf16x8*)((const char*)As + swz(wrow + m * 16 + (lane & 15), koffb));
#pragma unroll
      for (int n = 0; n < 4; ++n)
        bfr[n] = *(const bf16x8*)((const char*)Bs + swz(wcol + n * 16 + (lane & 15), koffb));
#pragma unroll
      for (int m = 0; m < 4; ++m)
#pragma unroll
        for (int n = 0; n < 4; ++n)
          acc[m][n] = __builtin_amdgcn_mfma_f32_16x16x32_bf16(af[m], bfr[n], acc[m][n], 0, 0, 0);
    }
    __syncthreads();
  }

#pragma unroll
  for (int i = 0; i < 8; ++i) {
#pragma unroll
    for (int mask = 1; mask < 16; mask <<= 1) {
      racc[i] += __shfl_xor(racc[i], mask, 64);
      cacc[i] += __shfl_xor(cacc[i], mask, 64);
    }
  }
  if ((t & 15) == 0) {
#pragma unroll
    for (int i = 0; i < 8; ++i) { sA[i * 16 + sr] = racc[i]; sB[i * 16 + sr] = cacc[i]; }
  }
  __syncthreads();

#pragma unroll
  for (int m = 0; m < 4; ++m) {
    const int rbase = wrow + m * 16 + (lane >> 4) * 4;
#pragma unroll
    for (int j = 0; j < 4; ++j) {
      const int row = rbase + j;
      const float ha = 0.5f * sA[row];
      float* orow = C + (size_t)(brow + row) * NM + bcol;
#pragma unroll
      for (int n = 0; n < 4; ++n) {
        const int col = wcol + n * 16 + (lane & 15);
        orow[col] = ha + 0.5f * sB[col] - acc[m][n][j];
      }
    }
  }
}

extern "C" void kernel_launch(void* const* d_in, const int* in_sizes, int n_in,
                              void* d_out, int out_size, void* d_ws, size_t ws_size,
                              hipStream_t stream) {
  const float* a = (const float*)d_in[0];
  const float* b = (const float*)d_in[1];
  float* out = (float*)d_out;

  const size_t mat_bytes = (size_t)NM * DD;  // 8 MB per i8 matrix
  const size_t need = 2 * mat_bytes + 2 * (size_t)NM * sizeof(float);

  if (ws_size >= need) {
    signed char* QA = (signed char*)d_ws;
    signed char* QB = (signed char*)d_ws + mat_bytes;
    float* RA = (float*)((char*)d_ws + 2 * mat_bytes);
    float* RB = RA + NM;
    hipLaunchKernelGGL(hell_prep8, dim3(2 * NM), dim3(256), 0, stream,
                       a, b, QA, QB, RA, RB);
    hipLaunchKernelGGL(hell_gemm19, dim3(32 * 32), dim3(512), 0, stream,
                       QA, QB, RA, RB, out);
  } else {
    dim3 grid(NM / 128, NM / 128);
    hipLaunchKernelGGL(hellinger_fused, grid, dim3(256), 0, stream, a, b, out);
  }
}